// Round 8
// baseline (156.766 us; speedup 1.0000x reference)
//
#include <hip/hip_runtime.h>
#include <hip/hip_bf16.h>

// Problem constants
#define S    2048
#define ND   128
#define NA   16
#define H    8
#define C    32
#define NH   24            // 3*H heads total
#define VD   128           // value dim per head
#define KQ_STRIDE (NH*C)   // 768 elems per row of K/Q
#define SCALE 0.3535533905932738f   // 1/sqrt(8)
#define SQS   0.5946035575013605f   // sqrt(SCALE)

// bf16 conversion-buffer element counts (flat regions in ws)
#define AN_SZ (S*ND)        // nodes bf16          262144
#define AA_SZ (S*32)        // aux  bf16 K-pad 32   65536
#define BN_SZ (512*ND)      // Wn   bf16            65536
#define BA_SZ (512*32)      // Wa   bf16 K-pad 32   16384
#define BV_SZ (3072*ND)     // Wv   bf16           393216
#define CONV_TOTAL (AN_SZ + AA_SZ + BN_SZ + BA_SZ + BV_SZ)  // 802816

typedef __attribute__((ext_vector_type(8))) short short8;
typedef __attribute__((ext_vector_type(4))) short s4v;
typedef __attribute__((ext_vector_type(4))) float f32x4;
typedef __attribute__((ext_vector_type(16))) float f32x16;

typedef __hip_bfloat16 bf16;

union U8 { short8 s; uint4 u; };

__device__ __forceinline__ short bf16_bits(float x) {
  bf16 h = __float2bfloat16(x);
  union { bf16 h; short s; } u; u.h = h; return u.s;
}

// ---------------------------------------------------------------------------
// Cast nodes/Wn/Wv to bf16; zero-pad aux/Wa from K=16 to K=32 (exact).
// ---------------------------------------------------------------------------
__global__ __launch_bounds__(256) void convert_kernel(
    const float* __restrict__ nodes, const float* __restrict__ aux,
    const float* __restrict__ Wn, const float* __restrict__ Wa,
    const float* __restrict__ Wv, bf16* __restrict__ out) {
  const int base = (blockIdx.x * 256 + threadIdx.x) * 4;
#pragma unroll
  for (int u = 0; u < 4; ++u) {
    const int idx = base + u;
    int k = idx;
    float v;
    if (k < AN_SZ) {
      v = nodes[k];
    } else if ((k -= AN_SZ) < AA_SZ) {
      const int ccol = k & 31;
      v = (ccol < 16) ? aux[(size_t)(k >> 5) * NA + ccol] : 0.0f;
    } else if ((k -= AA_SZ) < BN_SZ) {
      v = Wn[k];
    } else if ((k -= BN_SZ) < BA_SZ) {
      const int ccol = k & 31;
      v = (ccol < 16) ? Wa[(size_t)(k >> 5) * NA + ccol] : 0.0f;
    } else {
      v = Wv[k - BA_SZ];
    }
    out[idx] = __float2bfloat16(v);
  }
}

// ---------------------------------------------------------------------------
// MFMA projection GEMM. EPI 0: nodes k/q (K scaled by SCALE); 1: aux k/q
// (K scaled); 2: val^T. A rows i, B rows o; D[i][o].
// ---------------------------------------------------------------------------
template <int KE, int EPI>
__global__ __launch_bounds__(256) void gemm_proj_kernel(
    const bf16* __restrict__ A, const bf16* __restrict__ B,
    const float* __restrict__ bias,
    bf16* __restrict__ d0, bf16* __restrict__ d1) {
  const int t = threadIdx.x;
  const int lane = t & 63;
  const int w = t >> 6;
  const int l15 = lane & 15, g4 = lane >> 4;
  const int i0 = blockIdx.x * 64 + w * 16;
  const int o0 = blockIdx.y * 64;

  f32x4 acc[4];
#pragma unroll
  for (int s = 0; s < 4; ++s) acc[s] = (f32x4){0.f, 0.f, 0.f, 0.f};

  const bf16* arow = A + (size_t)(i0 + l15) * KE + g4 * 8;
  const bf16* brow = B + (size_t)(o0 + l15) * KE + g4 * 8;
#pragma unroll
  for (int ks = 0; ks < KE / 32; ++ks) {
    const short8 af = *reinterpret_cast<const short8*>(arow + ks * 32);
#pragma unroll
    for (int s = 0; s < 4; ++s) {
      const short8 bfr = *reinterpret_cast<const short8*>(
          brow + (size_t)s * 16 * KE + ks * 32);
      acc[s] = __builtin_amdgcn_mfma_f32_16x16x32_bf16(af, bfr, acc[s], 0, 0, 0);
    }
  }

#pragma unroll
  for (int s = 0; s < 4; ++s) {
    const int o = o0 + s * 16 + l15;
    const float bb = bias[o];
    if (EPI == 2) {
      s4v pk;
#pragma unroll
      for (int r = 0; r < 4; ++r) pk[r] = bf16_bits(acc[s][r] + bb);
      *reinterpret_cast<s4v*>(d0 + (size_t)o * S + i0 + g4 * 4) = pk;
    } else {
      const int head = (EPI == 0 ? 0 : 8) + (o >> 6);
      const int half = (o >> 5) & 1;
      const int c = o & 31;
      bf16* dst = half ? d1 : d0;
      const float sc = half ? 1.0f : SCALE;  // fold SCALE into K
#pragma unroll
      for (int r = 0; r < 4; ++r)
        dst[(size_t)(i0 + g4 * 4 + r) * KQ_STRIDE + head * C + c] =
            __float2bfloat16((acc[s][r] + bb) * sc);
    }
  }
}

// ---------------------------------------------------------------------------
// Rot-head precompute. M_h = (W_rk_h^T W_rq_h)*sqrt(SCALE); G_i = rot_i^T M_h.
// Emit bf16 hi/lo splits so rot scores run on the SAME MFMA path.
// ---------------------------------------------------------------------------
__global__ __launch_bounds__(256) void rotg_kernel(
    const float* __restrict__ rot, const float* __restrict__ Wr,
    bf16* __restrict__ Ghat, bf16* __restrict__ Rhat) {
  __shared__ float M[8][4][4];
  const int t = threadIdx.x;
  if (t < 128) {
    const int hl = t >> 4, a = (t >> 2) & 3, b = t & 3;
    float s = 0.0f;
#pragma unroll
    for (int c = 0; c < 32; ++c)
      s += Wr[(size_t)(hl * 64 + c) * 4 + a] * Wr[(size_t)(hl * 64 + 32 + c) * 4 + b];
    M[hl][a][b] = s * SQS;
  }
  __syncthreads();
  const int i  = blockIdx.x * 32 + (t >> 3);
  const int hl = t & 7;
  const float4 rv = *reinterpret_cast<const float4*>(rot + (size_t)i * 4);
  float g[4];
#pragma unroll
  for (int b = 0; b < 4; ++b)
    g[b] = rv.x * M[hl][0][b] + rv.y * M[hl][1][b]
         + rv.z * M[hl][2][b] + rv.w * M[hl][3][b];

  short hi[4], lo[4];
#pragma unroll
  for (int b = 0; b < 4; ++b) {
    bf16 hb = __float2bfloat16(g[b]);
    hi[b] = bf16_bits(g[b]);
    lo[b] = bf16_bits(g[b] - __bfloat162float(hb));
  }
  const short8 zz = {0, 0, 0, 0, 0, 0, 0, 0};
  short8 w0 = {hi[0], hi[1], hi[2], hi[3], lo[0], lo[1], lo[2], lo[3]};
  short8 w1 = {hi[0], hi[1], hi[2], hi[3], 0, 0, 0, 0};
  bf16* gp = Ghat + ((size_t)hl * S + i) * 32;
  *reinterpret_cast<short8*>(gp)      = w0;
  *reinterpret_cast<short8*>(gp + 8)  = w1;
  *reinterpret_cast<short8*>(gp + 16) = zz;
  *reinterpret_cast<short8*>(gp + 24) = zz;

  if (hl == 0) {
    float rr[4] = {rv.x, rv.y, rv.z, rv.w};
    short rh[4], rl[4];
#pragma unroll
    for (int b = 0; b < 4; ++b) {
      bf16 hb = __float2bfloat16(rr[b]);
      rh[b] = bf16_bits(rr[b]);
      rl[b] = bf16_bits(rr[b] - __bfloat162float(hb));
    }
    short8 r0 = {rh[0], rh[1], rh[2], rh[3], rh[0], rh[1], rh[2], rh[3]};
    short8 r1 = {rl[0], rl[1], rl[2], rl[3], 0, 0, 0, 0};
    bf16* rp = Rhat + (size_t)i * 32;
    *reinterpret_cast<short8*>(rp)      = r0;
    *reinterpret_cast<short8*>(rp + 8)  = r1;
    *reinterpret_cast<short8*>(rp + 16) = zz;
    *reinterpret_cast<short8*>(rp + 24) = zz;
  }
}

// ---------------------------------------------------------------------------
// 32x32-MFMA flash attention. Block = 4 waves: (wv = i-group of 32 rows,
// wj = j-parity). Swapped QK^T: sf = S^T[j][i], lane owns ONE i (l31),
// 32 j in regs; partner half-lane (^32) owns the other 32 j of the tile.
// P stays in registers: cvt_pk words feed PV B-frags directly; V stored in
// LDS with j bits 2<->3 swapped so A-slot j == B-slot j (any HW k-map
// cancels). Row stride 68 bf16 -> 2 lanes/bank (free). Exact pair-merge.
// MODE 1: per-head O to Op. MODE 2: atomicAdd into out.
// ---------------------------------------------------------------------------
template <int MODE>
__global__ __launch_bounds__(256) void attn_mfma_kernel(
    const bf16* __restrict__ Kb, const bf16* __restrict__ Qb,
    const bf16* __restrict__ Vt, const bf16* __restrict__ Ghat,
    const bf16* __restrict__ Rhat, float* __restrict__ Op) {
  const int hd   = blockIdx.y;
  const int i0   = blockIdx.x * 64;
  const int t    = threadIdx.x;
  const int lane = t & 63;
  const int w    = t >> 6;
  const int wv   = w & 1;       // i-group
  const int wj   = w >> 1;      // j-parity
  const int l31  = lane & 31;
  const int hf   = lane >> 5;
  const bool isrot = (hd >= 16);

  __shared__ __align__(16) char smem[34816];   // 2 x [128][68] bf16 V buffers
  bf16* myVs = (bf16*)(smem + wj * 17408);

  const bf16* kp; const bf16* qp; int kst, qst;
  if (!isrot) {
    kp = Kb + hd * C; qp = Qb + hd * C; kst = KQ_STRIDE; qst = KQ_STRIDE;
  } else {
    kp = Ghat + (size_t)(hd - 16) * S * 32; qp = Rhat; kst = 32; qst = 32;
  }

  const int irow = i0 + wv * 32 + l31;
  const bf16* krow = kp + (size_t)irow * kst;
  const short8 kf0 = *reinterpret_cast<const short8*>(krow + hf * 8);
  const short8 kf1 = *reinterpret_cast<const short8*>(krow + 16 + hf * 8);

  float m = -1e30f, l = 0.0f;
  f32x16 oacc[4];
#pragma unroll
  for (int d = 0; d < 4; ++d)
#pragma unroll
    for (int r = 0; r < 16; ++r) oacc[d][r] = 0.0f;

  // ---- staging: thread stages row sd of buffer sb (128B = full 64-j row) ----
  const int sb = t >> 7;
  const int sd = t & 127;
  const bf16* vsrc = Vt + ((size_t)hd * VD + sd) * S + sb * 64;
  bf16* wvs = (bf16*)(smem + sb * 17408) + sd * 68;

  U8 vg[8];
#pragma unroll
  for (int a = 0; a < 8; ++a)
    vg[a].s = *reinterpret_cast<const short8*>(vsrc + a * 8);

  // Q regs for first tile of my parity
  short8 q0, q1, q2, q3;
  {
    const bf16* qr = qp + (size_t)(wj * 64 + l31) * qst + hf * 8;
    q0 = *reinterpret_cast<const short8*>(qr);
    q1 = *reinterpret_cast<const short8*>(qr + 16);
    q2 = *reinterpret_cast<const short8*>(qr + (size_t)32 * qst);
    q3 = *reinterpret_cast<const short8*>(qr + (size_t)32 * qst + 16);
  }

  const bf16* vrd = myVs + l31 * 68 + hf * 8;   // PV read base

  for (int it = 0; it < S / 128; ++it) {
    __syncthreads();   // A: previous tile's LDS reads complete
    // commit staged V (j bits 2<->3 swapped: chunk a -> s base 4*(a&1)+16*(a>>1))
#pragma unroll
    for (int a = 0; a < 8; ++a) {
      const int off = 4 * (a & 1) + 16 * (a >> 1);
      uint2 lo; lo.x = vg[a].u.x; lo.y = vg[a].u.y;
      uint2 hi; hi.x = vg[a].u.z; hi.y = vg[a].u.w;
      *reinterpret_cast<uint2*>(wvs + off)     = lo;
      *reinterpret_cast<uint2*>(wvs + off + 8) = hi;
    }
    __syncthreads();   // B: LDS ready
    // prefetch next V tile into regs (T14: lands during compute)
    if (it + 1 < S / 128) {
      const bf16* p = vsrc + (size_t)(it + 1) * 128;
#pragma unroll
      for (int a = 0; a < 8; ++a)
        vg[a].s = *reinterpret_cast<const short8*>(p + a * 8);
    }

    // ---- QK: sf[jsub] = S^T, 32x32 tiles, K=32 via 2 k-steps ----
    f32x16 sf0, sf1;
    {
      const f32x16 z = {0,0,0,0,0,0,0,0,0,0,0,0,0,0,0,0};
      __builtin_amdgcn_s_setprio(1);
      sf0 = __builtin_amdgcn_mfma_f32_32x32x16_bf16(q0, kf0, z, 0, 0, 0);
      sf0 = __builtin_amdgcn_mfma_f32_32x32x16_bf16(q1, kf1, sf0, 0, 0, 0);
      sf1 = __builtin_amdgcn_mfma_f32_32x32x16_bf16(q2, kf0, z, 0, 0, 0);
      sf1 = __builtin_amdgcn_mfma_f32_32x32x16_bf16(q3, kf1, sf1, 0, 0, 0);
      __builtin_amdgcn_s_setprio(0);
    }
    // prefetch next Q
    if (it + 1 < S / 128) {
      const bf16* qr = qp + (size_t)((it + 1) * 128 + wj * 64 + l31) * qst + hf * 8;
      q0 = *reinterpret_cast<const short8*>(qr);
      q1 = *reinterpret_cast<const short8*>(qr + 16);
      q2 = *reinterpret_cast<const short8*>(qr + (size_t)32 * qst);
      q3 = *reinterpret_cast<const short8*>(qr + (size_t)32 * qst + 16);
    }

    if (isrot) {
#pragma unroll
      for (int r = 0; r < 16; ++r) { sf0[r] *= sf0[r]; sf1[r] *= sf1[r]; }
    }

    // ---- online softmax over j (32 in-lane + partner half-lane) ----
    float tm = sf0[0];
#pragma unroll
    for (int r = 1; r < 16; ++r) tm = fmaxf(tm, sf0[r]);
#pragma unroll
    for (int r = 0; r < 16; ++r) tm = fmaxf(tm, sf1[r]);
    tm = fmaxf(tm, __shfl_xor(tm, 32));
    if (__any(tm > m)) {
      const float mnew = fmaxf(m, tm);
      const float corr = __expf(m - mnew);
      m = mnew;
      l *= corr;
#pragma unroll
      for (int d = 0; d < 4; ++d)
#pragma unroll
        for (int r = 0; r < 16; ++r) oacc[d][r] *= corr;
    }
    float ls = 0.0f;
#pragma unroll
    for (int r = 0; r < 16; ++r) {
      const float p = __expf(sf0[r] - m); sf0[r] = p; ls += p;
    }
#pragma unroll
    for (int r = 0; r < 16; ++r) {
      const float p = __expf(sf1[r] - m); sf1[r] = p; ls += p;
    }
    ls += __shfl_xor(ls, 32);
    l += ls;

    // ---- PV: P in-register; B-frag = 4 contiguous cvt_pk words ----
    __builtin_amdgcn_s_setprio(1);
    {
      unsigned int pw[8];
#pragma unroll
      for (int q = 0; q < 8; ++q)
        asm volatile("v_cvt_pk_bf16_f32 %0, %1, %2"
                     : "=v"(pw[q]) : "v"(sf0[2 * q]), "v"(sf0[2 * q + 1]));
#pragma unroll
      for (int ks = 0; ks < 2; ++ks) {
        U8 pb;
        pb.u.x = pw[4 * ks]; pb.u.y = pw[4 * ks + 1];
        pb.u.z = pw[4 * ks + 2]; pb.u.w = pw[4 * ks + 3];
#pragma unroll
        for (int dt = 0; dt < 4; ++dt) {
          U8 va;
          uint2 x0 = *reinterpret_cast<const uint2*>(vrd + dt * 2176 + ks * 16);
          uint2 x1 = *reinterpret_cast<const uint2*>(vrd + dt * 2176 + ks * 16 + 4);
          va.u.x = x0.x; va.u.y = x0.y; va.u.z = x1.x; va.u.w = x1.y;
          oacc[dt] = __builtin_amdgcn_mfma_f32_32x32x16_bf16(va.s, pb.s,
                                                             oacc[dt], 0, 0, 0);
        }
      }
    }
    {
      unsigned int pw[8];
#pragma unroll
      for (int q = 0; q < 8; ++q)
        asm volatile("v_cvt_pk_bf16_f32 %0, %1, %2"
                     : "=v"(pw[q]) : "v"(sf1[2 * q]), "v"(sf1[2 * q + 1]));
#pragma unroll
      for (int ks = 2; ks < 4; ++ks) {
        U8 pb;
        pb.u.x = pw[4 * (ks - 2)]; pb.u.y = pw[4 * (ks - 2) + 1];
        pb.u.z = pw[4 * (ks - 2) + 2]; pb.u.w = pw[4 * (ks - 2) + 3];
#pragma unroll
        for (int dt = 0; dt < 4; ++dt) {
          U8 va;
          uint2 x0 = *reinterpret_cast<const uint2*>(vrd + dt * 2176 + ks * 16);
          uint2 x1 = *reinterpret_cast<const uint2*>(vrd + dt * 2176 + ks * 16 + 4);
          va.u.x = x0.x; va.u.y = x0.y; va.u.z = x1.x; va.u.w = x1.y;
          oacc[dt] = __builtin_amdgcn_mfma_f32_32x32x16_bf16(va.s, pb.s,
                                                             oacc[dt], 0, 0, 0);
        }
      }
    }
    __builtin_amdgcn_s_setprio(0);
  }

  // ---- exact pair-merge across j-parity (reuse Vs LDS) ----
  __syncthreads();
  float* Om = (float*)smem;                    // [64][132] f32
  float* ml = (float*)(smem + 33792);          // [64][2]
  const int il = wv * 32 + l31;
  if (wj == 1) {
    float* orow = Om + (size_t)il * 132;
#pragma unroll
    for (int dt = 0; dt < 4; ++dt)
#pragma unroll
      for (int qd = 0; qd < 4; ++qd) {
        const int d0 = dt * 32 + 8 * qd + 4 * hf;
        float4 v;
        v.x = oacc[dt][qd * 4 + 0]; v.y = oacc[dt][qd * 4 + 1];
        v.z = oacc[dt][qd * 4 + 2]; v.w = oacc[dt][qd * 4 + 3];
        *reinterpret_cast<float4*>(orow + d0) = v;
      }
    if (hf == 0) { ml[il * 2] = m; ml[il * 2 + 1] = l; }
  }
  __syncthreads();
  if (wj == 0) {
    const float m1 = ml[il * 2], l1 = ml[il * 2 + 1];
    const float M  = fmaxf(m, m1);
    const float w0 = __expf(m - M), w1 = __expf(m1 - M);
    const float inv = 1.0f / (w0 * l + w1 * l1);
    const float* orow = Om + (size_t)il * 132;
    if (MODE == 2) {
#pragma unroll
      for (int dt = 0; dt < 4; ++dt)
#pragma unroll
        for (int qd = 0; qd < 4; ++qd) {
          const int d0 = dt * 32 + 8 * qd + 4 * hf;
#pragma unroll
          for (int r = 0; r < 4; ++r)
            atomicAdd(Op + (size_t)irow * VD + d0 + r,
                      (w0 * oacc[dt][qd * 4 + r] + w1 * orow[d0 + r]) * inv);
        }
    } else {
      float* op = Op + (size_t)hd * (S * VD) + (size_t)irow * VD;
#pragma unroll
      for (int dt = 0; dt < 4; ++dt)
#pragma unroll
        for (int qd = 0; qd < 4; ++qd) {
          const int d0 = dt * 32 + 8 * qd + 4 * hf;
          float4 v;
          v.x = (w0 * oacc[dt][qd * 4 + 0] + w1 * orow[d0 + 0]) * inv;
          v.y = (w0 * oacc[dt][qd * 4 + 1] + w1 * orow[d0 + 1]) * inv;
          v.z = (w0 * oacc[dt][qd * 4 + 2] + w1 * orow[d0 + 2]) * inv;
          v.w = (w0 * oacc[dt][qd * 4 + 3] + w1 * orow[d0 + 3]) * inv;
          *reinterpret_cast<float4*>(op + d0) = v;
        }
    }
  }
}

// Sum the 24 per-head partials into the final (S, 128) output.
__global__ __launch_bounds__(256) void reduce_out_kernel(
    const float* __restrict__ OP, float* __restrict__ out) {
  const int idx = blockIdx.x * 256 + threadIdx.x;
  float s = 0.0f;
#pragma unroll
  for (int hh = 0; hh < NH; ++hh) s += OP[(size_t)hh * (S * VD) + idx];
  out[idx] = s;
}

extern "C" void kernel_launch(void* const* d_in, const int* in_sizes, int n_in,
                              void* d_out, int out_size, void* d_ws, size_t ws_size,
                              hipStream_t stream) {
  const float* nodes = (const float*)d_in[0];
  const float* aux   = (const float*)d_in[1];
  const float* rot   = (const float*)d_in[2];
  const float* Wn    = (const float*)d_in[3];
  const float* bn    = (const float*)d_in[4];
  const float* Wa    = (const float*)d_in[5];
  const float* ba    = (const float*)d_in[6];
  const float* Wr    = (const float*)d_in[7];
  const float* Wv    = (const float*)d_in[8];
  const float* bv    = (const float*)d_in[9];
  float* out = (float*)d_out;

  char* ws = (char*)d_ws;
  const size_t off_conv = 0;                                    // bf16 x 802816
  const size_t off_Kb   = off_conv + (size_t)CONV_TOTAL * 2;
  const size_t off_Qb   = off_Kb + (size_t)S * KQ_STRIDE * 2;
  const size_t off_Vt   = off_Qb + (size_t)S * KQ_STRIDE * 2;
  const size_t off_Gh   = off_Vt + (size_t)NH * VD * S * 2;     // 8*S*32 bf16
  const size_t off_Rh   = off_Gh + (size_t)8 * S * 32 * 2;      // S*32 bf16
  const size_t off_Op   = off_Rh + (size_t)S * 32 * 2;
  const size_t need1    = off_Op + (size_t)NH * S * VD * 4;     // ~46 MB

  bf16* convb = (bf16*)(ws + off_conv);
  bf16* An = convb;
  bf16* Aa = convb + AN_SZ;
  bf16* Bn = convb + AN_SZ + AA_SZ;
  bf16* Ba = convb + AN_SZ + AA_SZ + BN_SZ;
  bf16* Bv = convb + AN_SZ + AA_SZ + BN_SZ + BA_SZ;
  bf16*  Kb = (bf16*)(ws + off_Kb);
  bf16*  Qb = (bf16*)(ws + off_Qb);
  bf16*  Vt = (bf16*)(ws + off_Vt);
  bf16*  Gh = (bf16*)(ws + off_Gh);
  bf16*  Rh = (bf16*)(ws + off_Rh);
  float* Op = (float*)(ws + off_Op);

  convert_kernel<<<CONV_TOTAL / 1024, 256, 0, stream>>>(nodes, aux, Wn, Wa, Wv, convb);
  rotg_kernel<<<S / 32, 256, 0, stream>>>(rot, Wr, Gh, Rh);

  gemm_proj_kernel<128, 0><<<dim3(S / 64, 512 / 64), 256, 0, stream>>>(
      An, Bn, bn, Kb, Qb);
  gemm_proj_kernel<32, 1><<<dim3(S / 64, 512 / 64), 256, 0, stream>>>(
      Aa, Ba, ba, Kb, Qb);
  gemm_proj_kernel<128, 2><<<dim3(S / 64, 3072 / 64), 256, 0, stream>>>(
      An, Bv, bv, Vt, nullptr);

  if (ws_size >= need1) {
    attn_mfma_kernel<1><<<dim3(S / 64, NH), 256, 0, stream>>>(
        Kb, Qb, Vt, Gh, Rh, Op);
    reduce_out_kernel<<<(S * VD) / 256, 256, 0, stream>>>(Op, out);
  } else {
    hipMemsetAsync(d_out, 0, (size_t)out_size * sizeof(float), stream);
    attn_mfma_kernel<2><<<dim3(S / 64, NH), 256, 0, stream>>>(
        Kb, Qb, Vt, Gh, Rh, out);
  }
}

// Round 9
// 118.534 us; speedup vs baseline: 1.3225x; 1.3225x over previous
//
#include <hip/hip_runtime.h>
#include <hip/hip_bf16.h>
#include <hip/hip_fp16.h>

// Problem constants
#define S    2048
#define ND   128
#define NA   16
#define H    8
#define C    32
#define NH   24            // 3*H heads total
#define VD   128           // value dim per head
#define KQ_STRIDE (NH*C)   // 768 elems per row of K/Q
#define SCALE 0.3535533905932738f   // 1/sqrt(8)
// exp2-domain folding: scores arrive pre-multiplied by log2(e)
#define KSC 0.5101275365575154f     // SCALE * log2(e)  (folded into K)
#define GSC 0.7142321096986785f     // sqrt(KSC)        (folded into G; squares -> KSC)

// bf16 conversion-buffer element counts (flat regions in ws)
#define AN_SZ (S*ND)        // nodes bf16          262144
#define AA_SZ (S*32)        // aux  bf16 K-pad 32   65536
#define BN_SZ (512*ND)      // Wn   bf16            65536
#define BA_SZ (512*32)      // Wa   bf16 K-pad 32   16384
#define BV_SZ (3072*ND)     // Wv   bf16           393216
#define CONV_TOTAL (AN_SZ + AA_SZ + BN_SZ + BA_SZ + BV_SZ)  // 802816

typedef __attribute__((ext_vector_type(8))) short short8;
typedef __attribute__((ext_vector_type(4))) short s4v;
typedef __attribute__((ext_vector_type(4))) float f32x4;

typedef __hip_bfloat16 bf16;

__device__ __forceinline__ short bf16_bits(float x) {
  bf16 h = __float2bfloat16(x);
  union { bf16 h; short s; } u; u.h = h; return u.s;
}

__device__ __forceinline__ float fexp2(float x) { return __builtin_exp2f(x); }

// ---------------------------------------------------------------------------
// Cast nodes/Wn/Wv to bf16; zero-pad aux/Wa from K=16 to K=32 (exact).
// ---------------------------------------------------------------------------
__global__ __launch_bounds__(256) void convert_kernel(
    const float* __restrict__ nodes, const float* __restrict__ aux,
    const float* __restrict__ Wn, const float* __restrict__ Wa,
    const float* __restrict__ Wv, bf16* __restrict__ out) {
  const int base = (blockIdx.x * 256 + threadIdx.x) * 4;
#pragma unroll
  for (int u = 0; u < 4; ++u) {
    const int idx = base + u;
    int k = idx;
    float v;
    if (k < AN_SZ) {
      v = nodes[k];
    } else if ((k -= AN_SZ) < AA_SZ) {
      const int ccol = k & 31;
      v = (ccol < 16) ? aux[(size_t)(k >> 5) * NA + ccol] : 0.0f;
    } else if ((k -= AA_SZ) < BN_SZ) {
      v = Wn[k];
    } else if ((k -= BN_SZ) < BA_SZ) {
      const int ccol = k & 31;
      v = (ccol < 16) ? Wa[(size_t)(k >> 5) * NA + ccol] : 0.0f;
    } else {
      v = Wv[k - BA_SZ];
    }
    out[idx] = __float2bfloat16(v);
  }
}

// ---------------------------------------------------------------------------
// MFMA projection GEMM. EPI 0: nodes k/q (K scaled by KSC); 1: aux k/q
// (K scaled); 2: val^T. A rows i, B rows o; D[i][o].
// ---------------------------------------------------------------------------
template <int KE, int EPI>
__global__ __launch_bounds__(256) void gemm_proj_kernel(
    const bf16* __restrict__ A, const bf16* __restrict__ B,
    const float* __restrict__ bias,
    bf16* __restrict__ d0, bf16* __restrict__ d1) {
  const int t = threadIdx.x;
  const int lane = t & 63;
  const int w = t >> 6;
  const int l15 = lane & 15, g4 = lane >> 4;
  const int i0 = blockIdx.x * 64 + w * 16;
  const int o0 = blockIdx.y * 64;

  f32x4 acc[4];
#pragma unroll
  for (int s = 0; s < 4; ++s) acc[s] = (f32x4){0.f, 0.f, 0.f, 0.f};

  const bf16* arow = A + (size_t)(i0 + l15) * KE + g4 * 8;
  const bf16* brow = B + (size_t)(o0 + l15) * KE + g4 * 8;
#pragma unroll
  for (int ks = 0; ks < KE / 32; ++ks) {
    const short8 af = *reinterpret_cast<const short8*>(arow + ks * 32);
#pragma unroll
    for (int s = 0; s < 4; ++s) {
      const short8 bfr = *reinterpret_cast<const short8*>(
          brow + (size_t)s * 16 * KE + ks * 32);
      acc[s] = __builtin_amdgcn_mfma_f32_16x16x32_bf16(af, bfr, acc[s], 0, 0, 0);
    }
  }

#pragma unroll
  for (int s = 0; s < 4; ++s) {
    const int o = o0 + s * 16 + l15;
    const float bb = bias[o];
    if (EPI == 2) {
      s4v pk;
#pragma unroll
      for (int r = 0; r < 4; ++r) pk[r] = bf16_bits(acc[s][r] + bb);
      *reinterpret_cast<s4v*>(d0 + (size_t)o * S + i0 + g4 * 4) = pk;
    } else {
      const int head = (EPI == 0 ? 0 : 8) + (o >> 6);
      const int half = (o >> 5) & 1;
      const int c = o & 31;
      bf16* dst = half ? d1 : d0;
      const float sc = half ? 1.0f : KSC;  // fold SCALE*log2e into K
#pragma unroll
      for (int r = 0; r < 4; ++r)
        dst[(size_t)(i0 + g4 * 4 + r) * KQ_STRIDE + head * C + c] =
            __float2bfloat16((acc[s][r] + bb) * sc);
    }
  }
}

// ---------------------------------------------------------------------------
// Rot-head precompute. M_h = (W_rk_h^T W_rq_h)*GSC; G_i = rot_i^T M_h.
// Emit bf16 hi/lo splits so rot scores run on the SAME MFMA path.
// ---------------------------------------------------------------------------
__global__ __launch_bounds__(256) void rotg_kernel(
    const float* __restrict__ rot, const float* __restrict__ Wr,
    bf16* __restrict__ Ghat, bf16* __restrict__ Rhat) {
  __shared__ float M[8][4][4];
  const int t = threadIdx.x;
  if (t < 128) {
    const int hl = t >> 4, a = (t >> 2) & 3, b = t & 3;
    float s = 0.0f;
#pragma unroll
    for (int c = 0; c < 32; ++c)
      s += Wr[(size_t)(hl * 64 + c) * 4 + a] * Wr[(size_t)(hl * 64 + 32 + c) * 4 + b];
    M[hl][a][b] = s * GSC;
  }
  __syncthreads();
  const int i  = blockIdx.x * 32 + (t >> 3);
  const int hl = t & 7;
  const float4 rv = *reinterpret_cast<const float4*>(rot + (size_t)i * 4);
  float g[4];
#pragma unroll
  for (int b = 0; b < 4; ++b)
    g[b] = rv.x * M[hl][0][b] + rv.y * M[hl][1][b]
         + rv.z * M[hl][2][b] + rv.w * M[hl][3][b];

  short hi[4], lo[4];
#pragma unroll
  for (int b = 0; b < 4; ++b) {
    bf16 hb = __float2bfloat16(g[b]);
    hi[b] = bf16_bits(g[b]);
    lo[b] = bf16_bits(g[b] - __bfloat162float(hb));
  }
  const short8 zz = {0, 0, 0, 0, 0, 0, 0, 0};
  short8 w0 = {hi[0], hi[1], hi[2], hi[3], lo[0], lo[1], lo[2], lo[3]};
  short8 w1 = {hi[0], hi[1], hi[2], hi[3], 0, 0, 0, 0};
  bf16* gp = Ghat + ((size_t)hl * S + i) * 32;
  *reinterpret_cast<short8*>(gp)      = w0;
  *reinterpret_cast<short8*>(gp + 8)  = w1;
  *reinterpret_cast<short8*>(gp + 16) = zz;
  *reinterpret_cast<short8*>(gp + 24) = zz;

  if (hl == 0) {
    float rr[4] = {rv.x, rv.y, rv.z, rv.w};
    short rh[4], rl[4];
#pragma unroll
    for (int b = 0; b < 4; ++b) {
      bf16 hb = __float2bfloat16(rr[b]);
      rh[b] = bf16_bits(rr[b]);
      rl[b] = bf16_bits(rr[b] - __bfloat162float(hb));
    }
    short8 r0 = {rh[0], rh[1], rh[2], rh[3], rh[0], rh[1], rh[2], rh[3]};
    short8 r1 = {rl[0], rl[1], rl[2], rl[3], 0, 0, 0, 0};
    bf16* rp = Rhat + (size_t)i * 32;
    *reinterpret_cast<short8*>(rp)      = r0;
    *reinterpret_cast<short8*>(rp + 8)  = r1;
    *reinterpret_cast<short8*>(rp + 16) = zz;
    *reinterpret_cast<short8*>(rp + 24) = zz;
  }
}

// ---------------------------------------------------------------------------
// Swapped-layout MFMA flash attention (R6 structure), 2-tile unrolled.
// Static Vs0/Vs1 -> LDS addresses are base-VGPR + immediate. Q prefetched one
// tile ahead. setprio around MFMA. exp2-domain softmax (scores pre-scaled by
// log2e). Defer-max: skip O-rescale while max grows by <= 8 (exact).
// MODE 1: per-head fp16 O to Oph. MODE 2: atomicAdd float into out.
// ---------------------------------------------------------------------------
template <int MODE>
__global__ __launch_bounds__(256, 3) void attn_mfma_kernel(
    const bf16* __restrict__ Kb, const bf16* __restrict__ Qb,
    const bf16* __restrict__ Vt, const bf16* __restrict__ Ghat,
    const bf16* __restrict__ Rhat, __half* __restrict__ Oph,
    float* __restrict__ Opf) {
  const int h    = blockIdx.y;
  const int i0   = blockIdx.x * 64;
  const int t    = threadIdx.x;
  const int lane = t & 63;
  const int w    = t >> 6;
  const int l15  = lane & 15;
  const int g4   = lane >> 4;
  const bool isrot = (h >= 16);

  __shared__ __align__(16) bf16 Vs0[128 * 64];            // 16 KB each
  __shared__ __align__(16) bf16 Vs1[128 * 64];
  __shared__ __align__(16) unsigned int Ps[4][16][40];    // 10 KB

  const bf16* kp; const bf16* qp; int kst, qst;
  if (!isrot) {
    kp = Kb + h * C; qp = Qb + h * C; kst = KQ_STRIDE; qst = KQ_STRIDE;
  } else {
    kp = Ghat + (size_t)(h - 16) * S * 32; qp = Rhat; kst = 32; qst = 32;
  }

  // B-frag: K row for this wave's i = i0 + w*16 + l15 (loop-invariant)
  const short8 kfrag = *reinterpret_cast<const short8*>(
      kp + (size_t)(i0 + w * 16 + l15) * kst + g4 * 8);

  float m = -1e30f, l = 0.0f;
  f32x4 oacc[8];
#pragma unroll
  for (int d = 0; d < 8; ++d) oacc[d] = (f32x4){0.f, 0.f, 0.f, 0.f};

  // ---- thread-constant LDS offsets ----
  const int vd  = t >> 1;
  const int vjh4 = (t & 1) * 4;  // (vjh/8)
  const int wo0 = vd * 64 + (((vjh4 + 0) ^ (vd & 7)) << 3);
  const int wo1 = vd * 64 + (((vjh4 + 1) ^ (vd & 7)) << 3);
  const int wo2 = vd * 64 + (((vjh4 + 2) ^ (vd & 7)) << 3);
  const int wo3 = vd * 64 + (((vjh4 + 3) ^ (vd & 7)) << 3);
  const int vbase0 = l15 * 64 + (((g4 + 0) ^ (l15 & 7)) << 3);
  const int vbase1 = l15 * 64 + (((g4 + 4) ^ (l15 & 7)) << 3);

  const bf16* vsrc = Vt + ((size_t)h * VD + vd) * S + (t & 1) * 32;
  short8 vr0, vr1, vr2, vr3;
  short8 qA0, qA1, qA2, qA3, qB0, qB1, qB2, qB3;

  // ---- prologue: V(0)->Vs0, V(1)->regs, Q(0)->qA ----
  vr0 = *reinterpret_cast<const short8*>(vsrc);
  vr1 = *reinterpret_cast<const short8*>(vsrc + 8);
  vr2 = *reinterpret_cast<const short8*>(vsrc + 16);
  vr3 = *reinterpret_cast<const short8*>(vsrc + 24);
  *reinterpret_cast<short8*>(&Vs0[wo0]) = vr0;
  *reinterpret_cast<short8*>(&Vs0[wo1]) = vr1;
  *reinterpret_cast<short8*>(&Vs0[wo2]) = vr2;
  *reinterpret_cast<short8*>(&Vs0[wo3]) = vr3;
  vr0 = *reinterpret_cast<const short8*>(vsrc + 64);
  vr1 = *reinterpret_cast<const short8*>(vsrc + 72);
  vr2 = *reinterpret_cast<const short8*>(vsrc + 80);
  vr3 = *reinterpret_cast<const short8*>(vsrc + 88);
  {
    const bf16* qn = qp + (size_t)l15 * qst + g4 * 8;
    qA0 = *reinterpret_cast<const short8*>(qn);
    qA1 = *reinterpret_cast<const short8*>(qn + 16 * qst);
    qA2 = *reinterpret_cast<const short8*>(qn + 32 * qst);
    qA3 = *reinterpret_cast<const short8*>(qn + 48 * qst);
  }

#define TILE_BODY(VB_CUR, VB_NXT, Q0, Q1, Q2, Q3, QN0, QN1, QN2, QN3, J0)     \
  {                                                                           \
    __syncthreads();                                                          \
    if ((J0) + 64 < S) {                                                      \
      *reinterpret_cast<short8*>(&VB_NXT[wo0]) = vr0;                         \
      *reinterpret_cast<short8*>(&VB_NXT[wo1]) = vr1;                         \
      *reinterpret_cast<short8*>(&VB_NXT[wo2]) = vr2;                         \
      *reinterpret_cast<short8*>(&VB_NXT[wo3]) = vr3;                         \
      if ((J0) + 128 < S) {                                                   \
        const bf16* p = vsrc + (J0) + 128;                                    \
        vr0 = *reinterpret_cast<const short8*>(p);                            \
        vr1 = *reinterpret_cast<const short8*>(p + 8);                        \
        vr2 = *reinterpret_cast<const short8*>(p + 16);                       \
        vr3 = *reinterpret_cast<const short8*>(p + 24);                       \
      }                                                                       \
      const bf16* qn = qp + (size_t)((J0) + 64 + l15) * qst + g4 * 8;         \
      QN0 = *reinterpret_cast<const short8*>(qn);                             \
      QN1 = *reinterpret_cast<const short8*>(qn + 16 * qst);                  \
      QN2 = *reinterpret_cast<const short8*>(qn + 32 * qst);                  \
      QN3 = *reinterpret_cast<const short8*>(qn + 48 * qst);                  \
    }                                                                         \
    f32x4 sf[4];                                                              \
    {                                                                         \
      const f32x4 z = {0.f, 0.f, 0.f, 0.f};                                   \
      __builtin_amdgcn_s_setprio(1);                                          \
      sf[0] = __builtin_amdgcn_mfma_f32_16x16x32_bf16(Q0, kfrag, z, 0, 0, 0); \
      sf[1] = __builtin_amdgcn_mfma_f32_16x16x32_bf16(Q1, kfrag, z, 0, 0, 0); \
      sf[2] = __builtin_amdgcn_mfma_f32_16x16x32_bf16(Q2, kfrag, z, 0, 0, 0); \
      sf[3] = __builtin_amdgcn_mfma_f32_16x16x32_bf16(Q3, kfrag, z, 0, 0, 0); \
      __builtin_amdgcn_s_setprio(0);                                          \
    }                                                                         \
    if (isrot) {                                                              \
      _Pragma("unroll") for (int sub = 0; sub < 4; ++sub)                     \
          _Pragma("unroll") for (int r = 0; r < 4; ++r)                       \
              sf[sub][r] *= sf[sub][r];                                       \
    }                                                                         \
    float tm = sf[0][0];                                                      \
    _Pragma("unroll") for (int sub = 0; sub < 4; ++sub)                       \
        _Pragma("unroll") for (int r = 0; r < 4; ++r)                         \
            tm = fmaxf(tm, sf[sub][r]);                                       \
    tm = fmaxf(tm, __shfl_xor(tm, 16));                                       \
    tm = fmaxf(tm, __shfl_xor(tm, 32));                                       \
    if (__any(tm > m + 8.0f)) {                                               \
      const float mnew = fmaxf(m, tm);                                        \
      const float corr = fexp2(m - mnew);                                     \
      m = mnew;                                                               \
      l *= corr;                                                              \
      _Pragma("unroll") for (int d = 0; d < 8; ++d)                           \
          _Pragma("unroll") for (int r = 0; r < 4; ++r)                       \
              oacc[d][r] *= corr;                                             \
    }                                                                         \
    float ls = 0.0f;                                                          \
    _Pragma("unroll") for (int sub = 0; sub < 4; ++sub)                       \
        _Pragma("unroll") for (int r = 0; r < 4; ++r) {                       \
          const float p = fexp2(sf[sub][r] - m);                              \
          sf[sub][r] = p;                                                     \
          ls += p;                                                            \
        }                                                                     \
    ls += __shfl_xor(ls, 16);                                                 \
    ls += __shfl_xor(ls, 32);                                                 \
    l += ls;                                                                  \
    _Pragma("unroll") for (int sub = 0; sub < 4; ++sub) {                     \
      unsigned int u0, u1;                                                    \
      asm volatile("v_cvt_pk_bf16_f32 %0, %1, %2"                             \
                   : "=v"(u0) : "v"(sf[sub][0]), "v"(sf[sub][1]));            \
      asm volatile("v_cvt_pk_bf16_f32 %0, %1, %2"                             \
                   : "=v"(u1) : "v"(sf[sub][2]), "v"(sf[sub][3]));            \
      uint2 pk; pk.x = u0; pk.y = u1;                                         \
      *reinterpret_cast<uint2*>(&Ps[w][l15][sub * 8 + g4 * 2]) = pk;          \
    }                                                                         \
    {                                                                         \
      union { uint4 u; short8 s; } pb0, pb1;                                  \
      pb0.u = *reinterpret_cast<const uint4*>(&Ps[w][l15][g4 * 4]);           \
      pb1.u = *reinterpret_cast<const uint4*>(&Ps[w][l15][16 + g4 * 4]);      \
      __builtin_amdgcn_s_setprio(1);                                          \
      _Pragma("unroll") for (int dsub = 0; dsub < 8; ++dsub) {                \
        const short8 vb = *reinterpret_cast<const short8*>(                   \
            &VB_CUR[vbase0 + dsub * 1024]);                                   \
        oacc[dsub] =                                                          \
            __builtin_amdgcn_mfma_f32_16x16x32_bf16(vb, pb0.s, oacc[dsub], 0, 0, 0); \
      }                                                                       \
      _Pragma("unroll") for (int dsub = 0; dsub < 8; ++dsub) {                \
        const short8 vb = *reinterpret_cast<const short8*>(                   \
            &VB_CUR[vbase1 + dsub * 1024]);                                   \
        oacc[dsub] =                                                          \
            __builtin_amdgcn_mfma_f32_16x16x32_bf16(vb, pb1.s, oacc[dsub], 0, 0, 0); \
      }                                                                       \
      __builtin_amdgcn_s_setprio(0);                                          \
    }                                                                         \
  }

  for (int j0 = 0; j0 < S; j0 += 128) {
    TILE_BODY(Vs0, Vs1, qA0, qA1, qA2, qA3, qB0, qB1, qB2, qB3, j0);
    TILE_BODY(Vs1, Vs0, qB0, qB1, qB2, qB3, qA0, qA1, qA2, qA3, j0 + 64);
  }
#undef TILE_BODY

  const float inv = 1.0f / l;
  const int irow = i0 + w * 16 + l15;
  if (MODE == 2) {
#pragma unroll
    for (int dsub = 0; dsub < 8; ++dsub)
#pragma unroll
      for (int r = 0; r < 4; ++r)
        atomicAdd(Opf + (size_t)irow * VD + dsub * 16 + g4 * 4 + r,
                  oacc[dsub][r] * inv);
  } else {
    __half* op = Oph + (size_t)h * (S * VD) + (size_t)irow * VD;
#pragma unroll
    for (int dsub = 0; dsub < 8; ++dsub) {
      __half h0 = __float2half(oacc[dsub][0] * inv);
      __half h1 = __float2half(oacc[dsub][1] * inv);
      __half h2 = __float2half(oacc[dsub][2] * inv);
      __half h3 = __float2half(oacc[dsub][3] * inv);
      __half2 p0 = __halves2half2(h0, h1);
      __half2 p1 = __halves2half2(h2, h3);
      uint2 u;
      u.x = *reinterpret_cast<unsigned int*>(&p0);
      u.y = *reinterpret_cast<unsigned int*>(&p1);
      *reinterpret_cast<uint2*>(op + dsub * 16 + g4 * 4) = u;
    }
  }
}

// Sum the 24 per-head fp16 partials into the final (S, 128) fp32 output.
__global__ __launch_bounds__(256) void reduce_out_kernel(
    const __half* __restrict__ Op, float* __restrict__ out) {
  const int idx2 = (blockIdx.x * 256 + threadIdx.x) * 2;
  float s0 = 0.0f, s1 = 0.0f;
#pragma unroll
  for (int hh = 0; hh < NH; ++hh) {
    const __half2 hv = *reinterpret_cast<const __half2*>(
        Op + (size_t)hh * (S * VD) + idx2);
    const float2 f = __half22float2(hv);
    s0 += f.x;
    s1 += f.y;
  }
  float2 o; o.x = s0; o.y = s1;
  *reinterpret_cast<float2*>(out + idx2) = o;
}

extern "C" void kernel_launch(void* const* d_in, const int* in_sizes, int n_in,
                              void* d_out, int out_size, void* d_ws, size_t ws_size,
                              hipStream_t stream) {
  const float* nodes = (const float*)d_in[0];
  const float* aux   = (const float*)d_in[1];
  const float* rot   = (const float*)d_in[2];
  const float* Wn    = (const float*)d_in[3];
  const float* bn    = (const float*)d_in[4];
  const float* Wa    = (const float*)d_in[5];
  const float* ba    = (const float*)d_in[6];
  const float* Wr    = (const float*)d_in[7];
  const float* Wv    = (const float*)d_in[8];
  const float* bv    = (const float*)d_in[9];
  float* out = (float*)d_out;

  char* ws = (char*)d_ws;
  const size_t off_conv = 0;                                    // bf16 x 802816
  const size_t off_Kb   = off_conv + (size_t)CONV_TOTAL * 2;
  const size_t off_Qb   = off_Kb + (size_t)S * KQ_STRIDE * 2;
  const size_t off_Vt   = off_Qb + (size_t)S * KQ_STRIDE * 2;
  const size_t off_Gh   = off_Vt + (size_t)NH * VD * S * 2;     // 8*S*32 bf16
  const size_t off_Rh   = off_Gh + (size_t)8 * S * 32 * 2;      // S*32 bf16
  const size_t off_Op   = off_Rh + (size_t)S * 32 * 2;
  const size_t need1    = off_Op + (size_t)NH * S * VD * 2;     // fp16 partials

  bf16* convb = (bf16*)(ws + off_conv);
  bf16* An = convb;
  bf16* Aa = convb + AN_SZ;
  bf16* Bn = convb + AN_SZ + AA_SZ;
  bf16* Ba = convb + AN_SZ + AA_SZ + BN_SZ;
  bf16* Bv = convb + AN_SZ + AA_SZ + BN_SZ + BA_SZ;
  bf16*  Kb = (bf16*)(ws + off_Kb);
  bf16*  Qb = (bf16*)(ws + off_Qb);
  bf16*  Vt = (bf16*)(ws + off_Vt);
  bf16*  Gh = (bf16*)(ws + off_Gh);
  bf16*  Rh = (bf16*)(ws + off_Rh);
  __half* Oph = (__half*)(ws + off_Op);

  convert_kernel<<<CONV_TOTAL / 1024, 256, 0, stream>>>(nodes, aux, Wn, Wa, Wv, convb);
  rotg_kernel<<<S / 32, 256, 0, stream>>>(rot, Wr, Gh, Rh);

  gemm_proj_kernel<128, 0><<<dim3(S / 64, 512 / 64), 256, 0, stream>>>(
      An, Bn, bn, Kb, Qb);
  gemm_proj_kernel<32, 1><<<dim3(S / 64, 512 / 64), 256, 0, stream>>>(
      Aa, Ba, ba, Kb, Qb);
  gemm_proj_kernel<128, 2><<<dim3(S / 64, 3072 / 64), 256, 0, stream>>>(
      An, Bv, bv, Vt, nullptr);

  if (ws_size >= need1) {
    attn_mfma_kernel<1><<<dim3(S / 64, NH), 256, 0, stream>>>(
        Kb, Qb, Vt, Gh, Rh, Oph, nullptr);
    reduce_out_kernel<<<(S * VD) / 512, 256, 0, stream>>>(Oph, out);
  } else {
    hipMemsetAsync(d_out, 0, (size_t)out_size * sizeof(float), stream);
    attn_mfma_kernel<2><<<dim3(S / 64, NH), 256, 0, stream>>>(
        Kb, Qb, Vt, Gh, Rh, nullptr, out);
  }
}